// Round 6
// baseline (285.671 us; speedup 1.0000x reference)
//
#include <hip/hip_runtime.h>
#include <hip/hip_bf16.h>
#include <math.h>

// Problem dims
#define BATCH 8192
#define INF   1024
#define LEAFW 256
#define OUTF  1024
#define NLEAF 16
#define NNODE 15
#define NTOT  4096      // NLEAF * LEAFW
#define KEXT  4160      // 4096 + 64 (mixture @ B2 folded into GEMM2's K)

typedef __bf16 bf16;
typedef __bf16 bf16x4 __attribute__((ext_vector_type(4)));
typedef __bf16 bf16x8 __attribute__((ext_vector_type(8)));
typedef float  f32x4  __attribute__((ext_vector_type(4)));

// ---------------------------------------------------------------------------
// Merged weight-prep + gating kernel (unchanged from round 4).
__global__ __launch_bounds__(256) void prep_gk(
    const float* __restrict__ w1, const float* __restrict__ w2,
    const float* __restrict__ b2s, const float4* __restrict__ x4,
    const float4* __restrict__ nw4, const float* __restrict__ nb,
    bf16* __restrict__ W1T, bf16* __restrict__ W2T, float* __restrict__ mg,
    bf16* __restrict__ Aact, bf16x4* __restrict__ Xbf4) {
  __shared__ float tile[64][65];
  int b = blockIdx.x;
  int t = threadIdx.x;

  if (b < 2048) {  // ---- 64x64 transpose (w1 or w2) ----
    const float* src;
    bf16* dst;
    int srcld, dstld, r0, c0;
    if (b < 1024) {
      int l = b >> 6, rem = b & 63;
      r0 = (rem >> 2) * 64;
      c0 = (rem & 3) * 64;
      src = w1 + (size_t)l * INF * LEAFW;
      srcld = LEAFW;
      dst = W1T + (size_t)l * LEAFW * INF;
      dstld = INF;
    } else {
      int bb = b - 1024;
      int l = bb >> 6, rem = bb & 63;
      r0 = (rem >> 4) * 64;
      c0 = (rem & 15) * 64;
      src = w2 + (size_t)l * LEAFW * OUTF;
      srcld = OUTF;
      dst = W2T + l * LEAFW;
      dstld = KEXT;
    }
    int fr = t >> 4, hc4 = (t & 15) * 4;
#pragma unroll
    for (int p = 0; p < 4; ++p) {
      float4 v = *reinterpret_cast<const float4*>(
          &src[(size_t)(r0 + fr + p * 16) * srcld + c0 + hc4]);
      tile[fr + p * 16][hc4 + 0] = v.x;
      tile[fr + p * 16][hc4 + 1] = v.y;
      tile[fr + p * 16][hc4 + 2] = v.z;
      tile[fr + p * 16][hc4 + 3] = v.w;
    }
    __syncthreads();
#pragma unroll
    for (int p = 0; p < 2; ++p) {
      int s = t + p * 256;
      int h = s >> 3, fc = (s & 7) * 8;
      bf16x8 o;
#pragma unroll
      for (int e = 0; e < 8; ++e) o[e] = (bf16)tile[fc + e][h];
      *reinterpret_cast<bf16x8*>(&dst[(size_t)(c0 + h) * dstld + r0 + fc]) = o;
    }
    return;
  }

  if (b < 2304) {  // ---- W2T extension columns ----
    int i = (b - 2048) * 256 + t;
    int o = i >> 6, j = i & 63;
    W2T[(size_t)o * KEXT + NTOT + j] =
        (j < NLEAF) ? (bf16)b2s[(size_t)j * OUTF + o] : (bf16)0.f;
    return;
  }

  // ---- gating: one wave per row ----
  int row  = (b - 2304) * 4 + (t >> 6);
  int lane = t & 63;
  const float4* xr4 = x4 + (size_t)row * (INF / 4);

  float p[NNODE];
#pragma unroll
  for (int j = 0; j < NNODE; ++j) p[j] = 0.f;
#pragma unroll
  for (int c = 0; c < INF / 256; ++c) {
    int idx = c * 64 + lane;
    float4 xv = xr4[idx];
#pragma unroll
    for (int j = 0; j < NNODE; ++j) {
      float4 wv = nw4[j * (INF / 4) + idx];
      p[j] += xv.x * wv.x + xv.y * wv.y + xv.z * wv.z + xv.w * wv.w;
    }
    bf16x4 o = {(bf16)xv.x, (bf16)xv.y, (bf16)xv.z, (bf16)xv.w};
    Xbf4[(size_t)row * (INF / 4) + idx] = o;
  }
#pragma unroll
  for (int j = 0; j < NNODE; ++j) {
    float v = p[j];
#pragma unroll
    for (int off = 32; off > 0; off >>= 1) v += __shfl_xor(v, off);
    p[j] = 1.f / (1.f + expf(-(v + nb[j])));
  }
  float mixv[NLEAF];
#pragma unroll
  for (int L = 0; L < NLEAF; ++L) {
    int n1 = 1 + (L >> 3), n2 = 3 + (L >> 2), n3 = 7 + (L >> 1);
    float m = ((L >> 3) & 1) ? p[0] : (1.f - p[0]);
    m *= ((L >> 2) & 1) ? p[n1] : (1.f - p[n1]);
    m *= ((L >> 1) & 1) ? p[n2] : (1.f - p[n2]);
    m *= (L & 1) ? p[n3] : (1.f - p[n3]);
    mixv[L] = m;
  }
  bf16* arow = Aact + (size_t)row * KEXT + NTOT;
  if (lane == 0) {
#pragma unroll
    for (int L = 0; L < NLEAF; ++L) {
      mg[row * NLEAF + L] = mixv[L];
      arow[L] = (bf16)mixv[L];
    }
  }
  if (lane >= 16) arow[lane] = (bf16)0.f;
}

// ---------------------------------------------------------------------------
template <int N>
__device__ __forceinline__ void wait_vmcnt() {
  asm volatile("s_waitcnt vmcnt(%0)" ::"n"(N) : "memory");
}
__device__ __forceinline__ void barrier_fence() {
  asm volatile("" ::: "memory");
  __builtin_amdgcn_s_barrier();
  asm volatile("" ::: "memory");
}
__device__ __forceinline__ void lgkm0() {
  asm volatile("s_waitcnt lgkmcnt(0)" ::: "memory");
}

// ---------------------------------------------------------------------------
// GEMM1 — m201 8-phase schedule. 256x256 tile, BK=64, 8 waves (2M x 4N),
// per-wave out 128x64. 4 phases per K-tile, 16 MFMA each; quadrant order
// (A0,B0)(A0,B1)(A1,B1)(A1,B0). Each phase:
//   {ds_read ONE half-tile's frags for a LATER phase (4 or 8 x b128);
//    stage ONE half-tile of a future K-tile (2 x global_load_lds);
//    barrier; lgkmcnt(0); setprio(1); 16 MFMA (regs from prior phase);
//    setprio(0); [vmcnt(4) at P2/P4 only]; barrier}
// Stage leads its ds_read by 4 phases; vmcnt(4) at P2/P4 ends covers every
// read. vmcnt never 0 in loop. HALF-TILE SLOT = 128 rows x 64 cols x 2B
// = 16384 BYTES (round-5 bug: stage used 32768-byte stride vs 16384-byte
// read stride -> OOB LDS writes -> NaN. Fixed: both sides 16384.)
__global__ __launch_bounds__(512, 2) void g1_mfma(
    const bf16* __restrict__ A, const bf16* __restrict__ BT,
    const float* __restrict__ bias, const float* __restrict__ mg,
    bf16* __restrict__ outB) {
  constexpr int NT  = INF / 64;  // 16 K-tiles
  constexpr int HSZ = 128 * 64;  // elems per half-tile (16384 B)
  __shared__ __align__(16) bf16 As[4 * HSZ];  // [buf][half] 64 KiB
  __shared__ __align__(16) bf16 Bs[4 * HSZ];  // 64 KiB

  const int t = threadIdx.x, lane = t & 63, w = t >> 6;
  const int wm = w >> 2, wn = w & 3;
  // XCD-bijective swizzle: 512 blocks, 64 per XCD
  const int orig = blockIdx.x;
  const int swz  = (orig & 7) * 64 + (orig >> 3);
  const int bm = (swz >> 4) * 256, bn = (swz & 15) * 256;
  const int lr = t >> 3, cs = t & 7;
  const int scol = ((cs ^ (lr & 7)) << 3);  // XOR pre-swizzled global col

  auto stageA = [&](int kt, int h, int buf) {
#pragma unroll
    for (int q = 0; q < 2; ++q) {
      const bf16* src =
          A + (size_t)(bm + h * 128 + q * 64 + lr) * INF + kt * 64 + scol;
      __builtin_amdgcn_global_load_lds(
          (const __attribute__((address_space(1))) void*)src,
          (__attribute__((address_space(3))) void*)((char*)As +
                                                    (buf * 2 + h) * 16384 +
                                                    q * 8192 + t * 16),
          16, 0, 0);
    }
  };
  auto stageB = [&](int kt, int h, int buf) {
#pragma unroll
    for (int q = 0; q < 2; ++q) {
      const bf16* src =
          BT + (size_t)(bn + h * 128 + q * 64 + lr) * INF + kt * 64 + scol;
      __builtin_amdgcn_global_load_lds(
          (const __attribute__((address_space(1))) void*)src,
          (__attribute__((address_space(3))) void*)((char*)Bs +
                                                    (buf * 2 + h) * 16384 +
                                                    q * 8192 + t * 16),
          16, 0, 0);
    }
  };
  // ds_read one A-half (4 frags x 2 kk = 8 b128) / one B-half (2 x 2 = 4)
  auto rdAh = [&](int buf, int h, bf16x8 (&d)[4][2]) {
#pragma unroll
    for (int i = 0; i < 4; ++i)
#pragma unroll
      for (int kk = 0; kk < 2; ++kk) {
        int r  = wm * 64 + i * 16 + (lane & 15);
        int ch = ((kk << 2) + (lane >> 4)) ^ (lane & 7);
        d[i][kk] = *reinterpret_cast<const bf16x8*>(
            &As[(buf * 2 + h) * HSZ + r * 64 + ch * 8]);
      }
  };
  auto rdBh = [&](int buf, int h, bf16x8 (&d)[2][2]) {
#pragma unroll
    for (int j = 0; j < 2; ++j)
#pragma unroll
      for (int kk = 0; kk < 2; ++kk) {
        int r  = wn * 32 + j * 16 + (lane & 15);
        int ch = ((kk << 2) + (lane >> 4)) ^ (lane & 7);
        d[j][kk] = *reinterpret_cast<const bf16x8*>(
            &Bs[(buf * 2 + h) * HSZ + r * 64 + ch * 8]);
      }
  };

  f32x4 acc[8][4];
#pragma unroll
  for (int i = 0; i < 8; ++i)
#pragma unroll
    for (int j = 0; j < 4; ++j) acc[i][j] = (f32x4){0.f, 0.f, 0.f, 0.f};

  bf16x8 af0[4][2], af1[4][2], bq1[2][2], bq0a[2][2], bq0b[2][2];

  // Prologue: stage t0 {A0,B0,B1,A1} + t1 {A0,B0}; vmcnt(4) -> t0 landed.
  stageA(0, 0, 0);
  stageB(0, 0, 0);
  stageB(0, 1, 0);
  stageA(0, 1, 0);
  stageA(1, 0, 1);
  stageB(1, 0, 1);
  wait_vmcnt<4>();
  barrier_fence();
  rdAh(0, 0, af0);   // A0[0]
  rdBh(0, 0, bq0a);  // B0[0]

#define MFMA16(AF, BQ, IOFF, JOFF)                                          \
  __builtin_amdgcn_s_setprio(1);                                            \
  _Pragma("unroll") for (int kk = 0; kk < 2; ++kk) {                        \
    _Pragma("unroll") for (int i = 0; i < 4; ++i) {                         \
      _Pragma("unroll") for (int j = 0; j < 2; ++j) {                       \
        acc[(IOFF) + i][(JOFF) + j] =                                       \
            __builtin_amdgcn_mfma_f32_16x16x32_bf16(                        \
                AF[i][kk], BQ[j][kk], acc[(IOFF) + i][(JOFF) + j], 0, 0, 0);\
      }                                                                     \
    }                                                                       \
  }                                                                         \
  __builtin_amdgcn_s_setprio(0);

  // TILE(t): cur = t&1. BQ0C holds B0[t]; BQ0N receives B0[t+1].
#define TILE_STEP(T, CUR, BQ0C, BQ0N)                                       \
  {                                                                         \
    const int cur = (CUR), nxt = cur ^ 1;                                   \
    const int tp1 = ((T) + 1 < NT) ? (T) + 1 : NT - 1;                      \
    const int tp2 = ((T) + 2 < NT) ? (T) + 2 : NT - 1;                      \
    /* P1: compute (A0,B0); read B1[t]; stage B1[t+1] */                    \
    rdBh(cur, 1, bq1);                                                      \
    stageB(tp1, 1, nxt);                                                    \
    barrier_fence();                                                        \
    lgkm0();                                                                \
    MFMA16(af0, BQ0C, 0, 0);                                                \
    barrier_fence();                                                        \
    /* P2: compute (A0,B1); read A1[t]; stage A1[t+1]; vmcnt(4) */          \
    rdAh(cur, 1, af1);                                                      \
    stageA(tp1, 1, nxt);                                                    \
    barrier_fence();                                                        \
    lgkm0();                                                                \
    MFMA16(af0, bq1, 0, 2);                                                 \
    wait_vmcnt<4>();                                                        \
    barrier_fence();                                                        \
    /* P3: compute (A1,B1); read A0[t+1]; stage A0[t+2] */                  \
    rdAh(nxt, 0, af0);                                                      \
    stageA(tp2, 0, cur);                                                    \
    barrier_fence();                                                        \
    lgkm0();                                                                \
    MFMA16(af1, bq1, 4, 2);                                                 \
    barrier_fence();                                                        \
    /* P4: compute (A1,B0); read B0[t+1]; stage B0[t+2]; vmcnt(4) */        \
    rdBh(nxt, 0, BQ0N);                                                     \
    stageB(tp2, 0, cur);                                                    \
    barrier_fence();                                                        \
    lgkm0();                                                                \
    MFMA16(af1, BQ0C, 4, 0);                                                \
    wait_vmcnt<4>();                                                        \
    barrier_fence();                                                        \
  }

  for (int kt = 0; kt < NT; kt += 2) {
    TILE_STEP(kt, 0, bq0a, bq0b);
    TILE_STEP(kt + 1, 1, bq0b, bq0a);
  }
#undef TILE_STEP
#undef MFMA16

  // Epilogue: relu(acc + bias) * mg. C/D: col = lane&15, row = (lane>>4)*4+r
  const int leaf = bn >> 8;
#pragma unroll
  for (int i = 0; i < 8; ++i) {
    int rb = bm + (i >> 2) * 128 + wm * 64 + (i & 3) * 16 + ((lane >> 4) << 2);
#pragma unroll
    for (int rr = 0; rr < 4; ++rr) {
      const int grow = rb + rr;
      const float g  = mg[grow * NLEAF + leaf];
#pragma unroll
      for (int j = 0; j < 4; ++j) {
        const int gcol =
            bn + (j >> 1) * 128 + wn * 32 + (j & 1) * 16 + (lane & 15);
        float v = acc[i][j][rr] + bias[gcol];
        v = v > 0.f ? v : 0.f;
        outB[(size_t)grow * KEXT + gcol] = (bf16)(v * g);
      }
    }
  }
}

// ---------------------------------------------------------------------------
// GEMM2 (unchanged from rounds 3/4): 128x256 tile, 2-phase counted-vmcnt.
__global__ __launch_bounds__(512, 2) void g2_mfma(
    const bf16* __restrict__ A, const bf16* __restrict__ BT,
    float* __restrict__ outF) {
  constexpr int NT  = KEXT / 64;  // 65
  constexpr int ASZ = 128 * 64;
  constexpr int BSZ = 256 * 64;
  __shared__ __align__(16) bf16 As[2 * ASZ];
  __shared__ __align__(16) bf16 Bs[2 * BSZ];

  const int t = threadIdx.x, lane = t & 63, w = t >> 6;
  const int wm = w >> 2, wn = w & 3;
  const int orig = blockIdx.x;
  const int swz  = (orig & 7) * 32 + (orig >> 3);  // 256 blocks
  const int bm = (swz >> 2) * 128, bn = (swz & 3) * 256;
  const int lr = t >> 3, cs = t & 7;
  const int scol = ((cs ^ (lr & 7)) << 3);

  auto stageA = [&](int kt, int buf) {
#pragma unroll
    for (int q = 0; q < 2; ++q) {
      const bf16* src = A + (size_t)(bm + q * 64 + lr) * KEXT + kt * 64 + scol;
      __builtin_amdgcn_global_load_lds(
          (const __attribute__((address_space(1))) void*)src,
          (__attribute__((address_space(3))) void*)((char*)As +
                                                    buf * (ASZ * 2) +
                                                    q * 8192 + t * 16),
          16, 0, 0);
    }
  };
  auto stageB = [&](int kt, int h, int buf) {
#pragma unroll
    for (int q = 0; q < 2; ++q) {
      const bf16* src =
          BT + (size_t)(bn + h * 128 + q * 64 + lr) * KEXT + kt * 64 + scol;
      __builtin_amdgcn_global_load_lds(
          (const __attribute__((address_space(1))) void*)src,
          (__attribute__((address_space(3))) void*)((char*)Bs +
                                                    buf * (BSZ * 2) +
                                                    h * 16384 + q * 8192 +
                                                    t * 16),
          16, 0, 0);
    }
  };
  auto rdA = [&](int buf, int i, int kk) -> bf16x8 {
    int r  = (i >> 1) * 64 + wm * 32 + (i & 1) * 16 + (lane & 15);
    int ch = ((kk << 2) + (lane >> 4)) ^ (lane & 7);
    return *reinterpret_cast<const bf16x8*>(&As[buf * ASZ + r * 64 + ch * 8]);
  };
  auto rdB = [&](int buf, int j, int kk) -> bf16x8 {
    int r  = wn * 32 + (j & 1) * 16 + (lane & 15);
    int ch = ((kk << 2) + (lane >> 4)) ^ (lane & 7);
    return *reinterpret_cast<const bf16x8*>(
        &Bs[buf * BSZ + (j >> 1) * 8192 + r * 64 + ch * 8]);
  };

  f32x4 acc[4][4];
#pragma unroll
  for (int i = 0; i < 4; ++i)
#pragma unroll
    for (int j = 0; j < 4; ++j) acc[i][j] = (f32x4){0.f, 0.f, 0.f, 0.f};

  stageA(0, 0);
  stageB(0, 0, 0);
  stageB(0, 1, 0);
  wait_vmcnt<2>();
  barrier_fence();

  for (int kt = 0; kt < NT; ++kt) {
    const int cur = kt & 1, nxt = cur ^ 1;
    const int k1 = kt + 1 < NT ? kt + 1 : NT - 1;
    bf16x8 af[4][2], bq0[2][2], bq1[2][2];

#pragma unroll
    for (int i = 0; i < 4; ++i)
#pragma unroll
      for (int kk = 0; kk < 2; ++kk) af[i][kk] = rdA(cur, i, kk);
#pragma unroll
    for (int j = 0; j < 2; ++j)
#pragma unroll
      for (int kk = 0; kk < 2; ++kk) bq0[j][kk] = rdB(cur, j, kk);
    stageA(k1, nxt);
    stageB(k1, 0, nxt);
    __builtin_amdgcn_s_setprio(1);
#pragma unroll
    for (int kk = 0; kk < 2; ++kk)
#pragma unroll
      for (int i = 0; i < 4; ++i)
#pragma unroll
        for (int j = 0; j < 2; ++j)
          acc[i][j] = __builtin_amdgcn_mfma_f32_16x16x32_bf16(
              af[i][kk], bq0[j][kk], acc[i][j], 0, 0, 0);
    __builtin_amdgcn_s_setprio(0);
    wait_vmcnt<4>();
    barrier_fence();

#pragma unroll
    for (int j = 0; j < 2; ++j)
#pragma unroll
      for (int kk = 0; kk < 2; ++kk) bq1[j][kk] = rdB(cur, 2 + j, kk);
    stageB(k1, 1, nxt);
    __builtin_amdgcn_s_setprio(1);
#pragma unroll
    for (int kk = 0; kk < 2; ++kk)
#pragma unroll
      for (int i = 0; i < 4; ++i)
#pragma unroll
        for (int j = 0; j < 2; ++j)
          acc[i][2 + j] = __builtin_amdgcn_mfma_f32_16x16x32_bf16(
              af[i][kk], bq1[j][kk], acc[i][2 + j], 0, 0, 0);
    __builtin_amdgcn_s_setprio(0);
    wait_vmcnt<2>();
    barrier_fence();
  }

#pragma unroll
  for (int i = 0; i < 4; ++i) {
    int rb = bm + (i >> 1) * 64 + wm * 32 + (i & 1) * 16 + ((lane >> 4) << 2);
#pragma unroll
    for (int rr = 0; rr < 4; ++rr) {
      const int grow = rb + rr;
#pragma unroll
      for (int j = 0; j < 4; ++j) {
        const int gcol =
            bn + (j >> 1) * 128 + wn * 32 + (j & 1) * 16 + (lane & 15);
        outF[(size_t)grow * OUTF + gcol] = acc[i][j][rr];
      }
    }
  }
}

// ---------------------------------------------------------------------------
extern "C" void kernel_launch(void* const* d_in, const int* in_sizes, int n_in,
                              void* d_out, int out_size, void* d_ws,
                              size_t ws_size, hipStream_t stream) {
  const float* x   = (const float*)d_in[0];
  const float* nw  = (const float*)d_in[1];
  const float* nb  = (const float*)d_in[2];
  const float* w1s = (const float*)d_in[3];
  const float* b1s = (const float*)d_in[4];
  const float* w2s = (const float*)d_in[5];
  const float* b2s = (const float*)d_in[6];
  float* out = (float*)d_out;

  char* ws = (char*)d_ws;
  bf16*  Xbf  = (bf16*)(ws);                  // 16,777,216 B
  bf16*  W1T  = (bf16*)(ws + 16777216);       //  8,388,608 B  [4096][1024]
  bf16*  W2T  = (bf16*)(ws + 25165824);       //  8,519,680 B  [1024][4160]
  float* mg   = (float*)(ws + 33685504);      //    524,288 B  [8192][16]
  bf16*  Aact = (bf16*)(ws + 34209792);       // 68,157,440 B  [8192][4160]

  prep_gk<<<dim3(4352), 256, 0, stream>>>(
      w1s, w2s, b2s, (const float4*)x, (const float4*)nw, nb, W1T, W2T, mg,
      Aact, (bf16x4*)Xbf);

  // GEMM1: 256x256 tile, grid 32*16 = 512 blocks, m201 8-phase schedule
  g1_mfma<<<dim3(512), 512, 0, stream>>>(Xbf, W1T, b1s, mg, Aact);
  // GEMM2: 128x256 tile, grid 64*4 = 256 blocks, 2-phase schedule
  g2_mfma<<<dim3(256), 512, 0, stream>>>(Aact, W2T, out);
}

// Round 7
// 263.998 us; speedup vs baseline: 1.0821x; 1.0821x over previous
//
#include <hip/hip_runtime.h>
#include <hip/hip_bf16.h>
#include <math.h>

// Problem dims
#define BATCH 8192
#define INF   1024
#define LEAFW 256
#define OUTF  1024
#define NLEAF 16
#define NNODE 15
#define NTOT  4096      // NLEAF * LEAFW
#define KEXT  4160      // 4096 + 64 (mixture @ B2 folded into GEMM2's K)

typedef __bf16 bf16;
typedef __bf16 bf16x4 __attribute__((ext_vector_type(4)));
typedef __bf16 bf16x8 __attribute__((ext_vector_type(8)));
typedef float  f32x4  __attribute__((ext_vector_type(4)));

// ---------------------------------------------------------------------------
// Merged weight-prep + gating kernel (round-4 version, verbatim; passed).
__global__ __launch_bounds__(256) void prep_gk(
    const float* __restrict__ w1, const float* __restrict__ w2,
    const float* __restrict__ b2s, const float4* __restrict__ x4,
    const float4* __restrict__ nw4, const float* __restrict__ nb,
    bf16* __restrict__ W1T, bf16* __restrict__ W2T, float* __restrict__ mg,
    bf16* __restrict__ Aact, bf16x4* __restrict__ Xbf4) {
  __shared__ float tile[64][65];
  int b = blockIdx.x;
  int t = threadIdx.x;

  if (b < 2048) {  // ---- 64x64 transpose (w1 or w2) ----
    const float* src;
    bf16* dst;
    int srcld, dstld, r0, c0;
    if (b < 1024) {
      int l = b >> 6, rem = b & 63;
      r0 = (rem >> 2) * 64;
      c0 = (rem & 3) * 64;
      src = w1 + (size_t)l * INF * LEAFW;
      srcld = LEAFW;
      dst = W1T + (size_t)l * LEAFW * INF;
      dstld = INF;
    } else {
      int bb = b - 1024;
      int l = bb >> 6, rem = bb & 63;
      r0 = (rem >> 4) * 64;
      c0 = (rem & 15) * 64;
      src = w2 + (size_t)l * LEAFW * OUTF;
      srcld = OUTF;
      dst = W2T + l * LEAFW;
      dstld = KEXT;
    }
    int fr = t >> 4, hc4 = (t & 15) * 4;
#pragma unroll
    for (int p = 0; p < 4; ++p) {
      float4 v = *reinterpret_cast<const float4*>(
          &src[(size_t)(r0 + fr + p * 16) * srcld + c0 + hc4]);
      tile[fr + p * 16][hc4 + 0] = v.x;
      tile[fr + p * 16][hc4 + 1] = v.y;
      tile[fr + p * 16][hc4 + 2] = v.z;
      tile[fr + p * 16][hc4 + 3] = v.w;
    }
    __syncthreads();
#pragma unroll
    for (int p = 0; p < 2; ++p) {
      int s = t + p * 256;
      int h = s >> 3, fc = (s & 7) * 8;
      bf16x8 o;
#pragma unroll
      for (int e = 0; e < 8; ++e) o[e] = (bf16)tile[fc + e][h];
      *reinterpret_cast<bf16x8*>(&dst[(size_t)(c0 + h) * dstld + r0 + fc]) = o;
    }
    return;
  }

  if (b < 2304) {  // ---- W2T extension columns ----
    int i = (b - 2048) * 256 + t;
    int o = i >> 6, j = i & 63;
    W2T[(size_t)o * KEXT + NTOT + j] =
        (j < NLEAF) ? (bf16)b2s[(size_t)j * OUTF + o] : (bf16)0.f;
    return;
  }

  // ---- gating: one wave per row ----
  int row  = (b - 2304) * 4 + (t >> 6);
  int lane = t & 63;
  const float4* xr4 = x4 + (size_t)row * (INF / 4);

  float p[NNODE];
#pragma unroll
  for (int j = 0; j < NNODE; ++j) p[j] = 0.f;
#pragma unroll
  for (int c = 0; c < INF / 256; ++c) {
    int idx = c * 64 + lane;
    float4 xv = xr4[idx];
#pragma unroll
    for (int j = 0; j < NNODE; ++j) {
      float4 wv = nw4[j * (INF / 4) + idx];
      p[j] += xv.x * wv.x + xv.y * wv.y + xv.z * wv.z + xv.w * wv.w;
    }
    bf16x4 o = {(bf16)xv.x, (bf16)xv.y, (bf16)xv.z, (bf16)xv.w};
    Xbf4[(size_t)row * (INF / 4) + idx] = o;
  }
#pragma unroll
  for (int j = 0; j < NNODE; ++j) {
    float v = p[j];
#pragma unroll
    for (int off = 32; off > 0; off >>= 1) v += __shfl_xor(v, off);
    p[j] = 1.f / (1.f + expf(-(v + nb[j])));
  }
  float mixv[NLEAF];
#pragma unroll
  for (int L = 0; L < NLEAF; ++L) {
    int n1 = 1 + (L >> 3), n2 = 3 + (L >> 2), n3 = 7 + (L >> 1);
    float m = ((L >> 3) & 1) ? p[0] : (1.f - p[0]);
    m *= ((L >> 2) & 1) ? p[n1] : (1.f - p[n1]);
    m *= ((L >> 1) & 1) ? p[n2] : (1.f - p[n2]);
    m *= (L & 1) ? p[n3] : (1.f - p[n3]);
    mixv[L] = m;
  }
  bf16* arow = Aact + (size_t)row * KEXT + NTOT;
  if (lane == 0) {
#pragma unroll
    for (int L = 0; L < NLEAF; ++L) {
      mg[row * NLEAF + L] = mixv[L];
      arow[L] = (bf16)mixv[L];
    }
  }
  if (lane >= 16) arow[lane] = (bf16)0.f;
}

// ---------------------------------------------------------------------------
template <int N>
__device__ __forceinline__ void wait_vmcnt() {
  asm volatile("s_waitcnt vmcnt(%0)" ::"n"(N) : "memory");
}
__device__ __forceinline__ void barrier_fence() {
  asm volatile("" ::: "memory");
  __builtin_amdgcn_s_barrier();
  asm volatile("" ::: "memory");
}

// ---------------------------------------------------------------------------
// GEMM1 (round-2 winner, verbatim except dispatch order): 256x256 tile,
// 8 waves (2M x 4N), 4 phases/K-tile, ONE barrier per phase. Fragments read
// once per K-tile, held in registers across their two consuming phases.
// Phase order q(0,0) q(0,1) q(1,1) q(1,0).
// NEW: intra-XCD n-SLOW ordering — the 32 concurrent blocks per XCD span
// 8 B-panels (4 MB = one XCD L2) instead of 16 (8 MB, thrash).
__global__ __launch_bounds__(512, 2) void gemm1_kernel(
    const bf16* __restrict__ A, const bf16* __restrict__ BT,
    const float* __restrict__ bias, const float* __restrict__ mg,
    bf16* __restrict__ outB) {
  constexpr int NT  = INF / 64;      // 16 K-tiles
  constexpr int ASZ = 256 * 64;
  constexpr int BSZ = 256 * 64;
  __shared__ __align__(16) bf16 As[2 * ASZ];  // 64 KiB
  __shared__ __align__(16) bf16 Bs[2 * BSZ];  // 64 KiB

  const int t = threadIdx.x, lane = t & 63, w = t >> 6;
  const int wm = w >> 2, wn = w & 3;
  // XCD-bijective, n-slow within XCD: xcd = orig&7, idx = orig>>3 in [0,64);
  // m = xcd*4 + (idx&3)  (fast), n = idx>>2 (slow).
  const int orig = blockIdx.x;
  const int xcd  = orig & 7, idx = orig >> 3;
  const int bm = ((xcd << 2) + (idx & 3)) * 256;
  const int bn = (idx >> 2) * 256;
  const int lr = t >> 3, cs = t & 7;
  const int scol = ((cs ^ (lr & 7)) << 3);

  auto stageA = [&](int kt, int h, int buf) {
#pragma unroll
    for (int q = 0; q < 2; ++q) {
      const bf16* src =
          A + (size_t)(bm + h * 128 + q * 64 + lr) * INF + kt * 64 + scol;
      __builtin_amdgcn_global_load_lds(
          (const __attribute__((address_space(1))) void*)src,
          (__attribute__((address_space(3))) void*)((char*)As +
                                                    buf * (ASZ * 2) +
                                                    h * 16384 + q * 8192 +
                                                    t * 16),
          16, 0, 0);
    }
  };
  auto stageB = [&](int kt, int h, int buf) {
#pragma unroll
    for (int q = 0; q < 2; ++q) {
      const bf16* src =
          BT + (size_t)(bn + h * 128 + q * 64 + lr) * INF + kt * 64 + scol;
      __builtin_amdgcn_global_load_lds(
          (const __attribute__((address_space(1))) void*)src,
          (__attribute__((address_space(3))) void*)((char*)Bs +
                                                    buf * (BSZ * 2) +
                                                    h * 16384 + q * 8192 +
                                                    t * 16),
          16, 0, 0);
    }
  };
  auto rdA = [&](int buf, int i, int kk) -> bf16x8 {
    int r  = wm * 64 + (i & 3) * 16 + (lane & 15);
    int ch = ((kk << 2) + (lane >> 4)) ^ (lane & 7);
    return *reinterpret_cast<const bf16x8*>(
        &As[buf * ASZ + (i >> 2) * 8192 + r * 64 + ch * 8]);
  };
  auto rdB = [&](int buf, int j, int kk) -> bf16x8 {
    int r  = wn * 32 + (j & 1) * 16 + (lane & 15);
    int ch = ((kk << 2) + (lane >> 4)) ^ (lane & 7);
    return *reinterpret_cast<const bf16x8*>(
        &Bs[buf * BSZ + (j >> 1) * 8192 + r * 64 + ch * 8]);
  };

  f32x4 acc[8][4];
#pragma unroll
  for (int i = 0; i < 8; ++i)
#pragma unroll
    for (int j = 0; j < 4; ++j) acc[i][j] = (f32x4){0.f, 0.f, 0.f, 0.f};

  // Prologue: tile0 halves A0,B0,B1,A1; vmcnt(4) leaves {B1,A1} in flight.
  stageA(0, 0, 0);
  stageB(0, 0, 0);
  stageB(0, 1, 0);
  stageA(0, 1, 0);
  wait_vmcnt<4>();
  barrier_fence();

  for (int kt = 0; kt < NT; ++kt) {
    const int cur = kt & 1, nxt = cur ^ 1;
    const int k1 = kt + 1 < NT ? kt + 1 : NT - 1;
    bf16x8 af0[4][2], af1[4][2], bq0[2][2], bq1[2][2];

    // ---- P00: read A0,B0; stage (t+1).A0; MFMA quad (0,0)
#pragma unroll
    for (int i = 0; i < 4; ++i)
#pragma unroll
      for (int kk = 0; kk < 2; ++kk) af0[i][kk] = rdA(cur, i, kk);
#pragma unroll
    for (int j = 0; j < 2; ++j)
#pragma unroll
      for (int kk = 0; kk < 2; ++kk) bq0[j][kk] = rdB(cur, j, kk);
    stageA(k1, 0, nxt);
    __builtin_amdgcn_s_setprio(1);
#pragma unroll
    for (int kk = 0; kk < 2; ++kk)
#pragma unroll
      for (int i = 0; i < 4; ++i)
#pragma unroll
        for (int j = 0; j < 2; ++j)
          acc[i][j] = __builtin_amdgcn_mfma_f32_16x16x32_bf16(
              af0[i][kk], bq0[j][kk], acc[i][j], 0, 0, 0);
    __builtin_amdgcn_s_setprio(0);
    wait_vmcnt<4>();
    barrier_fence();

    // ---- P01: read B1; stage (t+1).B0; MFMA quad (0,1)
#pragma unroll
    for (int j = 0; j < 2; ++j)
#pragma unroll
      for (int kk = 0; kk < 2; ++kk) bq1[j][kk] = rdB(cur, 2 + j, kk);
    stageB(k1, 0, nxt);
    __builtin_amdgcn_s_setprio(1);
#pragma unroll
    for (int kk = 0; kk < 2; ++kk)
#pragma unroll
      for (int i = 0; i < 4; ++i)
#pragma unroll
        for (int j = 0; j < 2; ++j)
          acc[i][2 + j] = __builtin_amdgcn_mfma_f32_16x16x32_bf16(
              af0[i][kk], bq1[j][kk], acc[i][2 + j], 0, 0, 0);
    __builtin_amdgcn_s_setprio(0);
    wait_vmcnt<4>();
    barrier_fence();

    // ---- P11: read A1; stage (t+1).B1; MFMA quad (1,1)
#pragma unroll
    for (int i = 0; i < 4; ++i)
#pragma unroll
      for (int kk = 0; kk < 2; ++kk) af1[i][kk] = rdA(cur, 4 + i, kk);
    stageB(k1, 1, nxt);
    __builtin_amdgcn_s_setprio(1);
#pragma unroll
    for (int kk = 0; kk < 2; ++kk)
#pragma unroll
      for (int i = 0; i < 4; ++i)
#pragma unroll
        for (int j = 0; j < 2; ++j)
          acc[4 + i][2 + j] = __builtin_amdgcn_mfma_f32_16x16x32_bf16(
              af1[i][kk], bq1[j][kk], acc[4 + i][2 + j], 0, 0, 0);
    __builtin_amdgcn_s_setprio(0);
    wait_vmcnt<6>();
    barrier_fence();

    // ---- P10: stage (t+1).A1; MFMA quad (1,0) (af1, bq0 from registers)
    stageA(k1, 1, nxt);
    __builtin_amdgcn_s_setprio(1);
#pragma unroll
    for (int kk = 0; kk < 2; ++kk)
#pragma unroll
      for (int i = 0; i < 4; ++i)
#pragma unroll
        for (int j = 0; j < 2; ++j)
          acc[4 + i][j] = __builtin_amdgcn_mfma_f32_16x16x32_bf16(
              af1[i][kk], bq0[j][kk], acc[4 + i][j], 0, 0, 0);
    __builtin_amdgcn_s_setprio(0);
    wait_vmcnt<4>();
    barrier_fence();
  }

  // Epilogue: relu(acc + bias) * mg. C/D: col = lane&15, row = (lane>>4)*4+r
  const int leaf = bn >> 8;
#pragma unroll
  for (int i = 0; i < 8; ++i) {
    int rb = bm + (i >> 2) * 128 + wm * 64 + (i & 3) * 16 + ((lane >> 4) << 2);
#pragma unroll
    for (int rr = 0; rr < 4; ++rr) {
      const int grow = rb + rr;
      const float g  = mg[grow * NLEAF + leaf];
#pragma unroll
      for (int j = 0; j < 4; ++j) {
        const int gcol =
            bn + (j >> 1) * 128 + wn * 32 + (j & 1) * 16 + (lane & 15);
        float v = acc[i][j][rr] + bias[gcol];
        v = v > 0.f ? v : 0.f;
        outB[(size_t)grow * KEXT + gcol] = (bf16)(v * g);
      }
    }
  }
}

// ---------------------------------------------------------------------------
// GEMM2 (rounds-3/4 version, verbatim; passed): 128x256 tile, 2-phase
// counted-vmcnt, fp32 out.
__global__ __launch_bounds__(512, 2) void gemm2_kernel(
    const bf16* __restrict__ A, const bf16* __restrict__ BT,
    float* __restrict__ outF) {
  constexpr int NT  = KEXT / 64;  // 65
  constexpr int ASZ = 128 * 64;
  constexpr int BSZ = 256 * 64;
  __shared__ __align__(16) bf16 As[2 * ASZ];
  __shared__ __align__(16) bf16 Bs[2 * BSZ];

  const int t = threadIdx.x, lane = t & 63, w = t >> 6;
  const int wm = w >> 2, wn = w & 3;
  const int orig = blockIdx.x;
  const int swz  = (orig & 7) * 32 + (orig >> 3);  // 256 blocks
  const int bm = (swz >> 2) * 128, bn = (swz & 3) * 256;
  const int lr = t >> 3, cs = t & 7;
  const int scol = ((cs ^ (lr & 7)) << 3);

  auto stageA = [&](int kt, int buf) {
#pragma unroll
    for (int q = 0; q < 2; ++q) {
      const bf16* src = A + (size_t)(bm + q * 64 + lr) * KEXT + kt * 64 + scol;
      __builtin_amdgcn_global_load_lds(
          (const __attribute__((address_space(1))) void*)src,
          (__attribute__((address_space(3))) void*)((char*)As +
                                                    buf * (ASZ * 2) +
                                                    q * 8192 + t * 16),
          16, 0, 0);
    }
  };
  auto stageB = [&](int kt, int h, int buf) {
#pragma unroll
    for (int q = 0; q < 2; ++q) {
      const bf16* src =
          BT + (size_t)(bn + h * 128 + q * 64 + lr) * KEXT + kt * 64 + scol;
      __builtin_amdgcn_global_load_lds(
          (const __attribute__((address_space(1))) void*)src,
          (__attribute__((address_space(3))) void*)((char*)Bs +
                                                    buf * (BSZ * 2) +
                                                    h * 16384 + q * 8192 +
                                                    t * 16),
          16, 0, 0);
    }
  };
  auto rdA = [&](int buf, int i, int kk) -> bf16x8 {
    int r  = (i >> 1) * 64 + wm * 32 + (i & 1) * 16 + (lane & 15);
    int ch = ((kk << 2) + (lane >> 4)) ^ (lane & 7);
    return *reinterpret_cast<const bf16x8*>(&As[buf * ASZ + r * 64 + ch * 8]);
  };
  auto rdB = [&](int buf, int j, int kk) -> bf16x8 {
    int r  = wn * 32 + (j & 1) * 16 + (lane & 15);
    int ch = ((kk << 2) + (lane >> 4)) ^ (lane & 7);
    return *reinterpret_cast<const bf16x8*>(
        &Bs[buf * BSZ + (j >> 1) * 8192 + r * 64 + ch * 8]);
  };

  f32x4 acc[4][4];
#pragma unroll
  for (int i = 0; i < 4; ++i)
#pragma unroll
    for (int j = 0; j < 4; ++j) acc[i][j] = (f32x4){0.f, 0.f, 0.f, 0.f};

  stageA(0, 0);
  stageB(0, 0, 0);
  stageB(0, 1, 0);
  wait_vmcnt<2>();
  barrier_fence();

  for (int kt = 0; kt < NT; ++kt) {
    const int cur = kt & 1, nxt = cur ^ 1;
    const int k1 = kt + 1 < NT ? kt + 1 : NT - 1;
    bf16x8 af[4][2], bq0[2][2], bq1[2][2];

#pragma unroll
    for (int i = 0; i < 4; ++i)
#pragma unroll
      for (int kk = 0; kk < 2; ++kk) af[i][kk] = rdA(cur, i, kk);
#pragma unroll
    for (int j = 0; j < 2; ++j)
#pragma unroll
      for (int kk = 0; kk < 2; ++kk) bq0[j][kk] = rdB(cur, j, kk);
    stageA(k1, nxt);
    stageB(k1, 0, nxt);
    __builtin_amdgcn_s_setprio(1);
#pragma unroll
    for (int kk = 0; kk < 2; ++kk)
#pragma unroll
      for (int i = 0; i < 4; ++i)
#pragma unroll
        for (int j = 0; j < 2; ++j)
          acc[i][j] = __builtin_amdgcn_mfma_f32_16x16x32_bf16(
              af[i][kk], bq0[j][kk], acc[i][j], 0, 0, 0);
    __builtin_amdgcn_s_setprio(0);
    wait_vmcnt<4>();
    barrier_fence();

#pragma unroll
    for (int j = 0; j < 2; ++j)
#pragma unroll
      for (int kk = 0; kk < 2; ++kk) bq1[j][kk] = rdB(cur, 2 + j, kk);
    stageB(k1, 1, nxt);
    __builtin_amdgcn_s_setprio(1);
#pragma unroll
    for (int kk = 0; kk < 2; ++kk)
#pragma unroll
      for (int i = 0; i < 4; ++i)
#pragma unroll
        for (int j = 0; j < 2; ++j)
          acc[i][2 + j] = __builtin_amdgcn_mfma_f32_16x16x32_bf16(
              af[i][kk], bq1[j][kk], acc[i][2 + j], 0, 0, 0);
    __builtin_amdgcn_s_setprio(0);
    wait_vmcnt<2>();
    barrier_fence();
  }

#pragma unroll
  for (int i = 0; i < 4; ++i) {
    int rb = bm + (i >> 1) * 64 + wm * 32 + (i & 1) * 16 + ((lane >> 4) << 2);
#pragma unroll
    for (int rr = 0; rr < 4; ++rr) {
      const int grow = rb + rr;
#pragma unroll
      for (int j = 0; j < 4; ++j) {
        const int gcol =
            bn + (j >> 1) * 128 + wn * 32 + (j & 1) * 16 + (lane & 15);
        outF[(size_t)grow * OUTF + gcol] = acc[i][j][rr];
      }
    }
  }
}

// ---------------------------------------------------------------------------
extern "C" void kernel_launch(void* const* d_in, const int* in_sizes, int n_in,
                              void* d_out, int out_size, void* d_ws,
                              size_t ws_size, hipStream_t stream) {
  const float* x   = (const float*)d_in[0];
  const float* nw  = (const float*)d_in[1];
  const float* nb  = (const float*)d_in[2];
  const float* w1s = (const float*)d_in[3];
  const float* b1s = (const float*)d_in[4];
  const float* w2s = (const float*)d_in[5];
  const float* b2s = (const float*)d_in[6];
  float* out = (float*)d_out;

  char* ws = (char*)d_ws;
  bf16*  Xbf  = (bf16*)(ws);                  // 16,777,216 B
  bf16*  W1T  = (bf16*)(ws + 16777216);       //  8,388,608 B  [4096][1024]
  bf16*  W2T  = (bf16*)(ws + 25165824);       //  8,519,680 B  [1024][4160]
  float* mg   = (float*)(ws + 33685504);      //    524,288 B  [8192][16]
  bf16*  Aact = (bf16*)(ws + 34209792);       // 68,157,440 B  [8192][4160]

  prep_gk<<<dim3(4352), 256, 0, stream>>>(
      w1s, w2s, b2s, (const float4*)x, (const float4*)nw, nb, W1T, W2T, mg,
      Aact, (bf16x4*)Xbf);

  // GEMM1: 256x256 tile, grid 32*16 = 512 blocks, 4-phase, n-slow per XCD
  gemm1_kernel<<<dim3(512), 512, 0, stream>>>(Xbf, W1T, b1s, mg, Aact);
  // GEMM2: 128x256 tile, grid 64*4 = 256 blocks, 2-phase
  gemm2_kernel<<<dim3(256), 512, 0, stream>>>(Aact, W2T, out);
}